// Round 1
// baseline (357.484 us; speedup 1.0000x reference)
//
#include <hip/hip_runtime.h>
#include <hip/hip_bf16.h>
#include <cstdint>
#include <cstddef>

#define B_TOT   16384
#define F_DIM   1024
#define P_TOT   1024
#define K_IN    9
#define W_H     10
#define TB      64      // batch rows per block
#define THREADS 512     // 8 waves
#define NWAVE   8
#define LSTR    1026    // LDS row stride in bf16 elems; 1026/2=513 odd -> conflict-free gathers

__device__ __forceinline__ float fast_exp2(float x) {
#if __has_builtin(__builtin_amdgcn_exp2f)
    return __builtin_amdgcn_exp2f(x);
#else
    return exp2f(x);
#endif
}

__device__ __forceinline__ float fast_rcp(float x) {
#if __has_builtin(__builtin_amdgcn_rcpf)
    return __builtin_amdgcn_rcpf(x);
#else
    return 1.0f / x;
#endif
}

// tanh(x) = 1 - 2/(exp(2x)+1); exp(2x) = exp2(2*log2(e)*x). Robust at +-inf.
__device__ __forceinline__ float tanh_fast(float x) {
    float t = fast_exp2(x * 2.8853900817779268f);
    return fmaf(-2.0f, fast_rcp(t + 1.0f), 1.0f);
}

__device__ __forceinline__ uint32_t pack2_bf16(float a, float b) {
    union { __hip_bfloat162 h2; uint32_t u; } cv;
    cv.h2 = __float22bfloat162_rn(float2{a, b});
    return cv.u;
}

__global__ __launch_bounds__(THREADS, 1)
void dnn_fused(const float* __restrict__ x, const int* __restrict__ idx,
               const float* __restrict__ W1, const float* __restrict__ b1,
               const float* __restrict__ W2, const float* __restrict__ b2,
               const float* __restrict__ W3, const float* __restrict__ b3,
               const float* __restrict__ wl, float* __restrict__ out)
{
    extern __shared__ unsigned short xs[];       // [TB][LSTR] bf16 x tile
    __shared__ float partial[NWAVE][TB];

    const int tid = threadIdx.x;
    const int b0  = blockIdx.x * TB;

    // ---- stage x tile (fp32 global, coalesced float4) -> bf16 LDS ----
    #pragma unroll 4
    for (int i = 0; i < (TB * (F_DIM / 4)) / THREADS; ++i) {   // 32 iters
        const int q   = i * THREADS + tid;
        const int row = q >> 8;          // 256 float4 per row
        const int c4  = q & 255;
        const float4 v = *reinterpret_cast<const float4*>(
            x + (size_t)(b0 + row) * F_DIM + (c4 << 2));
        uint32_t* dst = reinterpret_cast<uint32_t*>(xs + row * LSTR + (c4 << 2));
        dst[0] = pack2_bf16(v.x, v.y);
        dst[1] = pack2_bf16(v.z, v.w);
    }
    __syncthreads();

    const int lane = tid & 63;           // lane = local batch row
    const int wave = tid >> 6;
    const unsigned short* __restrict__ myrow = xs + lane * LSTR;

    float yacc = 0.0f;

    for (int jp = 0; jp < P_TOT / NWAVE; ++jp) {
        // wave-uniform patch index -> weight loads become scalar s_loads
        const int p = __builtin_amdgcn_readfirstlane(jp * NWAVE + wave);
        const int*   __restrict__ ip  = idx + p * K_IN;
        const float* __restrict__ W1p = W1 + p * (K_IN * W_H);
        const float* __restrict__ b1p = b1 + p * W_H;
        const float* __restrict__ W2p = W2 + p * (W_H * W_H);
        const float* __restrict__ b2p = b2 + p * W_H;
        const float* __restrict__ W3p = W3 + p * W_H;

        // gather 9 features from LDS (conflict-free: 2 lanes/bank)
        float xg[K_IN];
        #pragma unroll
        for (int k = 0; k < K_IN; ++k) {
            const int c = ip[k];
            xg[k] = __uint_as_float(((uint32_t)myrow[c]) << 16);
        }

        // layer 1: (9 -> 10) + tanh
        float h1[W_H];
        #pragma unroll
        for (int w = 0; w < W_H; ++w) h1[w] = b1p[w];
        #pragma unroll
        for (int k = 0; k < K_IN; ++k)
            #pragma unroll
            for (int w = 0; w < W_H; ++w)
                h1[w] = fmaf(xg[k], W1p[k * W_H + w], h1[w]);
        #pragma unroll
        for (int w = 0; w < W_H; ++w) h1[w] = tanh_fast(h1[w]);

        // layer 2: (10 -> 10), linear
        float h2[W_H];
        #pragma unroll
        for (int v = 0; v < W_H; ++v) h2[v] = b2p[v];
        #pragma unroll
        for (int w = 0; w < W_H; ++w)
            #pragma unroll
            for (int v = 0; v < W_H; ++v)
                h2[v] = fmaf(h1[w], W2p[w * W_H + v], h2[v]);

        // layer 3: (10 -> 1), then weighted accumulate over p
        float lo = b3[p];
        #pragma unroll
        for (int w = 0; w < W_H; ++w) lo = fmaf(h2[w], W3p[w], lo);
        yacc = fmaf(lo, wl[p], yacc);
    }

    partial[wave][lane] = yacc;
    __syncthreads();

    // ---- block reduction over the 8 waves + outputs ----
    if (tid < TB) {
        float s = 0.0f;
        #pragma unroll
        for (int w = 0; w < NWAVE; ++w) s += partial[w][tid];
        out[b0 + tid] = s;

        // channel 2: sum(|w_last|), computed redundantly per block (wave 0 only)
        float sa = 0.0f;
        #pragma unroll
        for (int i = 0; i < P_TOT / TB; ++i) sa += fabsf(wl[tid + TB * i]);
        #pragma unroll
        for (int off = 32; off > 0; off >>= 1) sa += __shfl_down(sa, off);
        sa = __shfl(sa, 0);
        out[B_TOT + b0 + tid] = sa;
    }
}

extern "C" void kernel_launch(void* const* d_in, const int* in_sizes, int n_in,
                              void* d_out, int out_size, void* d_ws, size_t ws_size,
                              hipStream_t stream)
{
    const float* x  = (const float*)d_in[0];
    const int*   idx= (const int*)  d_in[1];
    const float* W1 = (const float*)d_in[2];
    const float* b1 = (const float*)d_in[3];
    const float* W2 = (const float*)d_in[4];
    const float* b2 = (const float*)d_in[5];
    const float* W3 = (const float*)d_in[6];
    const float* b3 = (const float*)d_in[7];
    const float* wl = (const float*)d_in[8];
    float* out = (float*)d_out;

    const int smem = TB * LSTR * 2;  // 131328 B dynamic LDS (>64KB -> opt in)
    hipFuncSetAttribute(reinterpret_cast<const void*>(dnn_fused),
                        hipFuncAttributeMaxDynamicSharedMemorySize, smem);

    dnn_fused<<<B_TOT / TB, THREADS, smem, stream>>>(x, idx, W1, b1, W2, b2, W3, b3, wl, out);
}

// Round 2
// 230.068 us; speedup vs baseline: 1.5538x; 1.5538x over previous
//
#include <hip/hip_runtime.h>
#include <hip/hip_bf16.h>
#include <cstdint>
#include <cstddef>

#define B_TOT   16384
#define F_DIM   1024
#define P_TOT   1024
#define K_IN    9
#define W_H     10
#define TB      64      // batch rows per block
#define THREADS 1024    // 16 waves
#define NWAVE   16
#define LSTR    1028    // LDS row stride in BYTES (fp8); 1028/4=257 -> lane*257 mod 32 distinct -> conflict-free gathers

__device__ __forceinline__ float fast_exp2(float x) {
#if __has_builtin(__builtin_amdgcn_exp2f)
    return __builtin_amdgcn_exp2f(x);
#else
    return exp2f(x);
#endif
}

__device__ __forceinline__ float fast_rcp(float x) {
#if __has_builtin(__builtin_amdgcn_rcpf)
    return __builtin_amdgcn_rcpf(x);
#else
    return 1.0f / x;
#endif
}

// tanh(x) = 1 - 2/(exp(2x)+1); exp(2x) = exp2(2*log2(e)*x). Robust at +-inf.
__device__ __forceinline__ float tanh_fast(float x) {
    float t = fast_exp2(x * 2.8853900817779268f);
    return fmaf(-2.0f, fast_rcp(t + 1.0f), 1.0f);
}

__global__ __launch_bounds__(THREADS, 1)
void dnn_fused(const float* __restrict__ x, const int* __restrict__ idx,
               const float* __restrict__ W1, const float* __restrict__ b1,
               const float* __restrict__ W2, const float* __restrict__ b2,
               const float* __restrict__ W3, const float* __restrict__ b3,
               const float* __restrict__ wl, float* __restrict__ out)
{
    extern __shared__ unsigned char xs[];        // [TB][LSTR] fp8(e4m3) x tile, 65792 B
    __shared__ float partial[NWAVE][TB];

    const int tid = threadIdx.x;
    const int b0  = blockIdx.x * TB;

    // ---- stage x tile (fp32 global, coalesced float4) -> fp8 LDS ----
    #pragma unroll
    for (int i = 0; i < (TB * (F_DIM / 4)) / THREADS; ++i) {   // 16 iters
        const int q   = i * THREADS + tid;
        const int row = q >> 8;          // 256 float4 per row
        const int c4  = q & 255;
        const float4 v = *reinterpret_cast<const float4*>(
            x + (size_t)(b0 + row) * F_DIM + (c4 << 2));
        int pk = __builtin_amdgcn_cvt_pk_fp8_f32(v.x, v.y, 0, false);   // low word
        pk     = __builtin_amdgcn_cvt_pk_fp8_f32(v.z, v.w, pk, true);   // high word
        *reinterpret_cast<uint32_t*>(xs + row * LSTR + (c4 << 2)) = (uint32_t)pk;
    }
    __syncthreads();

    const int lane = tid & 63;           // lane = local batch row
    const int wave = tid >> 6;
    const unsigned char* __restrict__ myrow = xs + lane * LSTR;

    float yacc = 0.0f;

    for (int jp = 0; jp < P_TOT / NWAVE; ++jp) {   // 64 iters
        // wave-uniform patch index -> weight loads become scalar s_loads
        const int p = __builtin_amdgcn_readfirstlane(jp * NWAVE + wave);
        const int*   __restrict__ ip  = idx + p * K_IN;
        const float* __restrict__ W1p = W1 + p * (K_IN * W_H);
        const float* __restrict__ b1p = b1 + p * W_H;
        const float* __restrict__ W2p = W2 + p * (W_H * W_H);
        const float* __restrict__ b2p = b2 + p * W_H;
        const float* __restrict__ W3p = W3 + p * W_H;

        // gather 9 features from LDS (conflict-free: stride 1028 B)
        float xg[K_IN];
        #pragma unroll
        for (int k = 0; k < K_IN; ++k) {
            const int c = ip[k];
            xg[k] = __builtin_amdgcn_cvt_f32_fp8((int)myrow[c], 0);
        }

        // layer 1: (9 -> 10) + tanh
        float h1[W_H];
        #pragma unroll
        for (int w = 0; w < W_H; ++w) h1[w] = b1p[w];
        #pragma unroll
        for (int k = 0; k < K_IN; ++k)
            #pragma unroll
            for (int w = 0; w < W_H; ++w)
                h1[w] = fmaf(xg[k], W1p[k * W_H + w], h1[w]);
        #pragma unroll
        for (int w = 0; w < W_H; ++w) h1[w] = tanh_fast(h1[w]);

        // layer 2: (10 -> 10), linear
        float h2[W_H];
        #pragma unroll
        for (int v = 0; v < W_H; ++v) h2[v] = b2p[v];
        #pragma unroll
        for (int w = 0; w < W_H; ++w)
            #pragma unroll
            for (int v = 0; v < W_H; ++v)
                h2[v] = fmaf(h1[w], W2p[w * W_H + v], h2[v]);

        // layer 3: (10 -> 1), then weighted accumulate over p
        float lo = b3[p];
        #pragma unroll
        for (int w = 0; w < W_H; ++w) lo = fmaf(h2[w], W3p[w], lo);
        yacc = fmaf(lo, wl[p], yacc);
    }

    partial[wave][lane] = yacc;
    __syncthreads();

    // ---- block reduction over the 16 waves + outputs ----
    if (tid < TB) {
        float s = 0.0f;
        #pragma unroll
        for (int w = 0; w < NWAVE; ++w) s += partial[w][tid];
        out[b0 + tid] = s;

        // channel 2: sum(|w_last|), computed redundantly per block (wave 0 only)
        float sa = 0.0f;
        #pragma unroll
        for (int i = 0; i < P_TOT / TB; ++i) sa += fabsf(wl[tid + TB * i]);
        #pragma unroll
        for (int off = 32; off > 0; off >>= 1) sa += __shfl_down(sa, off);
        sa = __shfl(sa, 0);
        out[B_TOT + b0 + tid] = sa;
    }
}

extern "C" void kernel_launch(void* const* d_in, const int* in_sizes, int n_in,
                              void* d_out, int out_size, void* d_ws, size_t ws_size,
                              hipStream_t stream)
{
    const float* x  = (const float*)d_in[0];
    const int*   idx= (const int*)  d_in[1];
    const float* W1 = (const float*)d_in[2];
    const float* b1 = (const float*)d_in[3];
    const float* W2 = (const float*)d_in[4];
    const float* b2 = (const float*)d_in[5];
    const float* W3 = (const float*)d_in[6];
    const float* b3 = (const float*)d_in[7];
    const float* wl = (const float*)d_in[8];
    float* out = (float*)d_out;

    const int smem = TB * LSTR;  // 65792 B dynamic LDS (>64KB -> opt in)
    hipFuncSetAttribute(reinterpret_cast<const void*>(dnn_fused),
                        hipFuncAttributeMaxDynamicSharedMemorySize, smem);

    dnn_fused<<<B_TOT / TB, THREADS, smem, stream>>>(x, idx, W1, b1, W2, b2, W3, b3, wl, out);
}

// Round 3
// 193.422 us; speedup vs baseline: 1.8482x; 1.1895x over previous
//
#include <hip/hip_runtime.h>
#include <hip/hip_bf16.h>
#include <cstdint>
#include <cstddef>

#define B_TOT   16384
#define F_DIM   1024
#define P_TOT   1024
#define K_IN    9
#define W_H     10
#define TB      64      // batch rows per block
#define THREADS 1024    // 16 waves
#define NWAVE   16
#define PGRP    2       // patch groups (P split across blocks)
#define PPB     (P_TOT / PGRP)   // 512 patches per block
#define LSTR    1028    // LDS row stride in BYTES (fp8); 1028/4=257 -> lane*257 mod 32 distinct -> conflict-free gathers

__device__ __forceinline__ float fast_exp2(float x) {
#if __has_builtin(__builtin_amdgcn_exp2f)
    return __builtin_amdgcn_exp2f(x);
#else
    return exp2f(x);
#endif
}

__device__ __forceinline__ float fast_rcp(float x) {
#if __has_builtin(__builtin_amdgcn_rcpf)
    return __builtin_amdgcn_rcpf(x);
#else
    return 1.0f / x;
#endif
}

// tanh(x) = 1 - 2/(exp(2x)+1); exp(2x) = exp2(2*log2(e)*x). Robust at +-inf.
__device__ __forceinline__ float tanh_fast(float x) {
    float t = fast_exp2(x * 2.8853900817779268f);
    return fmaf(-2.0f, fast_rcp(t + 1.0f), 1.0f);
}

__global__ __launch_bounds__(THREADS, 8)
void dnn_fused(const float* __restrict__ x, const int* __restrict__ idx,
               const float* __restrict__ W1, const float* __restrict__ b1,
               const float* __restrict__ W2, const float* __restrict__ b2,
               const float* __restrict__ W3, const float* __restrict__ b3,
               const float* __restrict__ wl, float* __restrict__ out)
{
    extern __shared__ unsigned char xs[];        // [TB][LSTR] fp8(e4m3) x tile, 65792 B
    __shared__ float partial[NWAVE][TB];

    const int tid = threadIdx.x;
    const int b0  = blockIdx.x * TB;
    const int p0  = blockIdx.y * PPB;

    // ---- stage x tile (fp32 global, coalesced float4) -> fp8 LDS ----
    #pragma unroll
    for (int i = 0; i < (TB * (F_DIM / 4)) / THREADS; ++i) {   // 16 iters
        const int q   = i * THREADS + tid;
        const int row = q >> 8;          // 256 float4 per row
        const int c4  = q & 255;
        const float4 v = *reinterpret_cast<const float4*>(
            x + (size_t)(b0 + row) * F_DIM + (c4 << 2));
        int pk = __builtin_amdgcn_cvt_pk_fp8_f32(v.x, v.y, 0, false);   // low word
        pk     = __builtin_amdgcn_cvt_pk_fp8_f32(v.z, v.w, pk, true);   // high word
        *reinterpret_cast<uint32_t*>(xs + row * LSTR + (c4 << 2)) = (uint32_t)pk;
    }
    __syncthreads();

    const int lane = tid & 63;           // lane = local batch row
    const int wave = tid >> 6;
    const unsigned char* __restrict__ myrow = xs + lane * LSTR;

    float yacc = 0.0f;

    for (int jp = 0; jp < PPB / NWAVE; ++jp) {   // 32 iters
        // wave-uniform patch index -> weight loads become scalar s_loads
        const int p = __builtin_amdgcn_readfirstlane(p0 + jp * NWAVE + wave);
        const int*   __restrict__ ip  = idx + p * K_IN;
        const float* __restrict__ W1p = W1 + p * (K_IN * W_H);
        const float* __restrict__ b1p = b1 + p * W_H;
        const float* __restrict__ W2p = W2 + p * (W_H * W_H);
        const float* __restrict__ b2p = b2 + p * W_H;
        const float* __restrict__ W3p = W3 + p * W_H;

        // gather 9 features from LDS (conflict-free: stride 1028 B)
        float xg[K_IN];
        #pragma unroll
        for (int k = 0; k < K_IN; ++k) {
            const int c = ip[k];
            xg[k] = __builtin_amdgcn_cvt_f32_fp8((int)myrow[c], 0);
        }

        // layer 1: (9 -> 10) + tanh
        float h1[W_H];
        #pragma unroll
        for (int w = 0; w < W_H; ++w) h1[w] = b1p[w];
        #pragma unroll
        for (int k = 0; k < K_IN; ++k)
            #pragma unroll
            for (int w = 0; w < W_H; ++w)
                h1[w] = fmaf(xg[k], W1p[k * W_H + w], h1[w]);
        #pragma unroll
        for (int w = 0; w < W_H; ++w) h1[w] = tanh_fast(h1[w]);

        // layer 2: (10 -> 10), linear
        float h2[W_H];
        #pragma unroll
        for (int v = 0; v < W_H; ++v) h2[v] = b2p[v];
        #pragma unroll
        for (int w = 0; w < W_H; ++w)
            #pragma unroll
            for (int v = 0; v < W_H; ++v)
                h2[v] = fmaf(h1[w], W2p[w * W_H + v], h2[v]);

        // layer 3: (10 -> 1), then weighted accumulate over p
        float lo = b3[p];
        #pragma unroll
        for (int w = 0; w < W_H; ++w) lo = fmaf(h2[w], W3p[w], lo);
        yacc = fmaf(lo, wl[p], yacc);
    }

    partial[wave][lane] = yacc;
    __syncthreads();

    // ---- block reduction over the 16 waves + outputs ----
    if (tid < TB) {
        float s = 0.0f;
        #pragma unroll
        for (int w = 0; w < NWAVE; ++w) s += partial[w][tid];
        // two blocks (pgroups) contribute to each y element; fp32 add is
        // commutative -> bitwise deterministic regardless of arrival order
        atomicAdd(&out[b0 + tid], s);

        if (blockIdx.y == 0) {
            // channel 2: sum(|w_last|), computed redundantly per row-block
            float sa = 0.0f;
            #pragma unroll
            for (int i = 0; i < P_TOT / TB; ++i) sa += fabsf(wl[tid + TB * i]);
            #pragma unroll
            for (int off = 32; off > 0; off >>= 1) sa += __shfl_down(sa, off);
            sa = __shfl(sa, 0);
            out[B_TOT + b0 + tid] = sa;   // direct store (single writer)
        }
    }
}

extern "C" void kernel_launch(void* const* d_in, const int* in_sizes, int n_in,
                              void* d_out, int out_size, void* d_ws, size_t ws_size,
                              hipStream_t stream)
{
    const float* x  = (const float*)d_in[0];
    const int*   idx= (const int*)  d_in[1];
    const float* W1 = (const float*)d_in[2];
    const float* b1 = (const float*)d_in[3];
    const float* W2 = (const float*)d_in[4];
    const float* b2 = (const float*)d_in[5];
    const float* W3 = (const float*)d_in[6];
    const float* b3 = (const float*)d_in[7];
    const float* wl = (const float*)d_in[8];
    float* out = (float*)d_out;

    // zero the y channel (atomicAdd accumulates into it)
    hipMemsetAsync(out, 0, B_TOT * sizeof(float), stream);

    const int smem = TB * LSTR;  // 65792 B dynamic LDS (>64KB -> opt in)
    hipFuncSetAttribute(reinterpret_cast<const void*>(dnn_fused),
                        hipFuncAttributeMaxDynamicSharedMemorySize, smem);

    dim3 grid(B_TOT / TB, PGRP);
    dnn_fused<<<grid, THREADS, smem, stream>>>(x, idx, W1, b1, W2, b2, W3, b3, wl, out);
}

// Round 8
// 155.053 us; speedup vs baseline: 2.3056x; 1.2475x over previous
//
#include <hip/hip_runtime.h>
#include <hip/hip_bf16.h>
#include <cstdint>
#include <cstddef>

#define B_TOT   16384
#define F_DIM   1024
#define P_TOT   1024
#define K_IN    9
#define W_H     10
#define TB      64      // batch rows per block
#define THREADS 1024    // 16 waves
#define NWAVE   16
#define PGRP    2       // patch groups (P split across blocks)
#define PPB     (P_TOT / PGRP)   // 512 patches per block
#define LSTR    1028    // LDS row stride in BYTES (fp8); conflict-free gathers

typedef float f32x2 __attribute__((ext_vector_type(2)));

__device__ __forceinline__ float fast_exp2(float x) {
#if __has_builtin(__builtin_amdgcn_exp2f)
    return __builtin_amdgcn_exp2f(x);
#else
    return exp2f(x);
#endif
}
__device__ __forceinline__ float fast_rcp(float x) {
#if __has_builtin(__builtin_amdgcn_rcpf)
    return __builtin_amdgcn_rcpf(x);
#else
    return 1.0f / x;
#endif
}
// tanh(x) = 1 - 2/(exp(2x)+1); robust at +-inf
__device__ __forceinline__ float tanh_fast(float x) {
    float t = fast_exp2(x * 2.8853900817779268f);
    return fmaf(-2.0f, fast_rcp(t + 1.0f), 1.0f);
}
__device__ __forceinline__ f32x2 ld2(const float* p) {
    return *reinterpret_cast<const f32x2*>(p);   // 8-aligned: all uses at even float offsets
}
__device__ __forceinline__ f32x2 pkfma(f32x2 a, f32x2 b, f32x2 c) {
#if __has_builtin(__builtin_elementwise_fma)
    return __builtin_elementwise_fma(a, b, c);   // -> v_pk_fma_f32 (FeaturePackedFP32Ops)
#else
    return f32x2{fmaf(a[0], b[0], c[0]), fmaf(a[1], b[1], c[1])};
#endif
}

__global__ __launch_bounds__(THREADS, 8)
void dnn_fused(const float* __restrict__ x, const int* __restrict__ idx,
               const float* __restrict__ W1, const float* __restrict__ b1,
               const float* __restrict__ W2, const float* __restrict__ b2,
               const float* __restrict__ W3, const float* __restrict__ b3,
               const float* __restrict__ wl, float* __restrict__ out)
{
    extern __shared__ unsigned char xs[];        // [TB][LSTR] fp8(e4m3) x tile
    __shared__ float partial[NWAVE][TB];

    const int tid = threadIdx.x;
    const int b0  = blockIdx.x * TB;
    const int p0  = blockIdx.y * PPB;

    // ---- stage x tile (fp32 global, coalesced float4) -> fp8 LDS ----
    #pragma unroll
    for (int i = 0; i < (TB * (F_DIM / 4)) / THREADS; ++i) {   // 16 iters
        const int q   = i * THREADS + tid;
        const int row = q >> 8;
        const int c4  = q & 255;
        const float4 v = *reinterpret_cast<const float4*>(
            x + (size_t)(b0 + row) * F_DIM + (c4 << 2));
        int pk = __builtin_amdgcn_cvt_pk_fp8_f32(v.x, v.y, 0, false);
        pk     = __builtin_amdgcn_cvt_pk_fp8_f32(v.z, v.w, pk, true);
        *reinterpret_cast<uint32_t*>(xs + row * LSTR + (c4 << 2)) = (uint32_t)pk;
    }
    __syncthreads();

    const int lane = tid & 63;           // lane = local batch row
    const int wave = tid >> 6;
    const unsigned char* __restrict__ myrow = xs + lane * LSTR;

    float yacc = 0.0f;

    for (int jp = 0; jp < PPB / NWAVE; ++jp) {   // 32 iters
        // wave-uniform patch index -> weight loads become scalar s_loads
        const int p = __builtin_amdgcn_readfirstlane(p0 + jp * NWAVE + wave);
        const int*   __restrict__ ip  = idx + p * K_IN;
        const float* __restrict__ W1p = W1 + p * (K_IN * W_H);
        const float* __restrict__ b1p = b1 + p * W_H;
        const float* __restrict__ W2p = W2 + p * (W_H * W_H);
        const float* __restrict__ b2p = b2 + p * W_H;
        const float* __restrict__ W3p = W3 + p * W_H;

        // gather 9 features from LDS (conflict-free: stride 1028 B)
        float xg[K_IN];
        #pragma unroll
        for (int k = 0; k < K_IN; ++k)
            xg[k] = __builtin_amdgcn_cvt_f32_fp8((int)myrow[ip[k]], 0);

        // layer 1: (9 -> 10) + tanh, packed fp32 over output pairs
        f32x2 H[5];
        #pragma unroll
        for (int j = 0; j < 5; ++j) H[j] = ld2(b1p + 2 * j);
        #pragma unroll
        for (int k = 0; k < K_IN; ++k) {
            const f32x2 xk2 = {xg[k], xg[k]};
            #pragma unroll
            for (int j = 0; j < 5; ++j)
                H[j] = pkfma(xk2, ld2(W1p + k * W_H + 2 * j), H[j]);
        }
        float h1[W_H];
        #pragma unroll
        for (int j = 0; j < 5; ++j) {
            h1[2 * j]     = tanh_fast(H[j][0]);
            h1[2 * j + 1] = tanh_fast(H[j][1]);
        }

        // layer 2: (10 -> 10), packed fp32 over output pairs
        f32x2 G[5];
        #pragma unroll
        for (int j = 0; j < 5; ++j) G[j] = ld2(b2p + 2 * j);
        #pragma unroll
        for (int w = 0; w < W_H; ++w) {
            const f32x2 hw2 = {h1[w], h1[w]};
            #pragma unroll
            for (int j = 0; j < 5; ++j)
                G[j] = pkfma(hw2, ld2(W2p + w * W_H + 2 * j), G[j]);
        }

        // layer 3: (10 -> 1), packed pairwise then horizontal add
        f32x2 acc2 = {b3[p], 0.0f};
        #pragma unroll
        for (int j = 0; j < 5; ++j)
            acc2 = pkfma(G[j], ld2(W3p + 2 * j), acc2);
        const float lo = acc2[0] + acc2[1];

        yacc = fmaf(lo, wl[p], yacc);
    }

    partial[wave][lane] = yacc;
    __syncthreads();

    // ---- block reduction over the 16 waves + outputs ----
    if (tid < TB) {
        float s = 0.0f;
        #pragma unroll
        for (int w = 0; w < NWAVE; ++w) s += partial[w][tid];
        // two blocks (pgroups) contribute per y element; fp32 add is
        // commutative -> bitwise deterministic regardless of arrival order
        atomicAdd(&out[b0 + tid], s);

        if (blockIdx.y == 0) {
            // channel 2: sum(|w_last|), computed redundantly per row-block
            float sa = 0.0f;
            #pragma unroll
            for (int i = 0; i < P_TOT / TB; ++i) sa += fabsf(wl[tid + TB * i]);
            #pragma unroll
            for (int off = 32; off > 0; off >>= 1) sa += __shfl_down(sa, off);
            sa = __shfl(sa, 0);
            out[B_TOT + b0 + tid] = sa;   // single writer
        }
    }
}

extern "C" void kernel_launch(void* const* d_in, const int* in_sizes, int n_in,
                              void* d_out, int out_size, void* d_ws, size_t ws_size,
                              hipStream_t stream)
{
    const float* x  = (const float*)d_in[0];
    const int*   idx= (const int*)  d_in[1];
    const float* W1 = (const float*)d_in[2];
    const float* b1 = (const float*)d_in[3];
    const float* W2 = (const float*)d_in[4];
    const float* b2 = (const float*)d_in[5];
    const float* W3 = (const float*)d_in[6];
    const float* b3 = (const float*)d_in[7];
    const float* wl = (const float*)d_in[8];
    float* out = (float*)d_out;

    // zero the y channel (atomicAdd accumulates into it)
    (void)hipMemsetAsync(out, 0, B_TOT * sizeof(float), stream);

    const int smem = TB * LSTR;  // 65792 B dynamic LDS (>64KB -> opt in)
    (void)hipFuncSetAttribute(reinterpret_cast<const void*>(dnn_fused),
                              hipFuncAttributeMaxDynamicSharedMemorySize, smem);

    dim3 grid(B_TOT / TB, PGRP);
    dnn_fused<<<grid, THREADS, smem, stream>>>(x, idx, W1, b1, W2, b2, W3, b3, wl, out);
}

// Round 9
// 154.145 us; speedup vs baseline: 2.3191x; 1.0059x over previous
//
#include <hip/hip_runtime.h>
#include <hip/hip_bf16.h>
#include <cstdint>
#include <cstddef>

#define B_TOT   16384
#define F_DIM   1024
#define P_TOT   1024
#define K_IN    9
#define W_H     10
#define TB      64      // batch rows per block
#define THREADS 1024    // 16 waves
#define NWAVE   16
#define PGRP    2       // patch groups (P split across blocks)
#define PPB     (P_TOT / PGRP)   // 512 patches per block
#define LSTR    1028    // LDS row stride in BYTES (fp8); conflict-free gathers

typedef float f32x2 __attribute__((ext_vector_type(2)));

__device__ __forceinline__ float fast_exp2(float x) {
#if __has_builtin(__builtin_amdgcn_exp2f)
    return __builtin_amdgcn_exp2f(x);
#else
    return exp2f(x);
#endif
}
__device__ __forceinline__ float fast_rcp(float x) {
#if __has_builtin(__builtin_amdgcn_rcpf)
    return __builtin_amdgcn_rcpf(x);
#else
    return 1.0f / x;
#endif
}
// tanh(x) = 1 - 2/(exp(2x)+1); robust at +-inf
__device__ __forceinline__ float tanh_fast(float x) {
    float t = fast_exp2(x * 2.8853900817779268f);
    return fmaf(-2.0f, fast_rcp(t + 1.0f), 1.0f);
}
__device__ __forceinline__ f32x2 ld2(const float* p) {
    return *reinterpret_cast<const f32x2*>(p);   // 8-aligned: all uses at even float offsets
}
__device__ __forceinline__ f32x2 pkfma(f32x2 a, f32x2 b, f32x2 c) {
#if __has_builtin(__builtin_elementwise_fma)
    return __builtin_elementwise_fma(a, b, c);   // -> v_pk_fma_f32 (FeaturePackedFP32Ops)
#else
    return f32x2{fmaf(a[0], b[0], c[0]), fmaf(a[1], b[1], c[1])};
#endif
}

// one patch's full MLP for this lane's batch row; straight-line so the
// scheduler can interleave two independent instances
__device__ __forceinline__ float patch_eval(
    const unsigned char* __restrict__ myrow, int p,
    const int* __restrict__ idx,
    const float* __restrict__ W1, const float* __restrict__ b1,
    const float* __restrict__ W2, const float* __restrict__ b2,
    const float* __restrict__ W3, const float* __restrict__ b3)
{
    const int*   __restrict__ ip  = idx + p * K_IN;
    const float* __restrict__ W1p = W1 + p * (K_IN * W_H);
    const float* __restrict__ b1p = b1 + p * W_H;
    const float* __restrict__ W2p = W2 + p * (W_H * W_H);
    const float* __restrict__ b2p = b2 + p * W_H;
    const float* __restrict__ W3p = W3 + p * W_H;

    // gather 9 features from LDS (conflict-free: stride 1028 B)
    float xg[K_IN];
    #pragma unroll
    for (int k = 0; k < K_IN; ++k)
        xg[k] = __builtin_amdgcn_cvt_f32_fp8((int)myrow[ip[k]], 0);

    // layer 1: (9 -> 10) + tanh, packed fp32 over output pairs
    f32x2 H[5];
    #pragma unroll
    for (int j = 0; j < 5; ++j) H[j] = ld2(b1p + 2 * j);
    #pragma unroll
    for (int k = 0; k < K_IN; ++k) {
        const f32x2 xk2 = {xg[k], xg[k]};
        #pragma unroll
        for (int j = 0; j < 5; ++j)
            H[j] = pkfma(xk2, ld2(W1p + k * W_H + 2 * j), H[j]);
    }
    float h1[W_H];
    #pragma unroll
    for (int j = 0; j < 5; ++j) {
        h1[2 * j]     = tanh_fast(H[j][0]);
        h1[2 * j + 1] = tanh_fast(H[j][1]);
    }

    // layer 2: (10 -> 10), packed fp32 over output pairs
    f32x2 G[5];
    #pragma unroll
    for (int j = 0; j < 5; ++j) G[j] = ld2(b2p + 2 * j);
    #pragma unroll
    for (int w = 0; w < W_H; ++w) {
        const f32x2 hw2 = {h1[w], h1[w]};
        #pragma unroll
        for (int j = 0; j < 5; ++j)
            G[j] = pkfma(hw2, ld2(W2p + w * W_H + 2 * j), G[j]);
    }

    // layer 3: (10 -> 1), packed pairwise then horizontal add
    f32x2 acc2 = {b3[p], 0.0f};
    #pragma unroll
    for (int j = 0; j < 5; ++j)
        acc2 = pkfma(G[j], ld2(W3p + 2 * j), acc2);
    return acc2[0] + acc2[1];
}

__global__ __launch_bounds__(THREADS, 8)
void dnn_fused(const float* __restrict__ x, const int* __restrict__ idx,
               const float* __restrict__ W1, const float* __restrict__ b1,
               const float* __restrict__ W2, const float* __restrict__ b2,
               const float* __restrict__ W3, const float* __restrict__ b3,
               const float* __restrict__ wl, float* __restrict__ out)
{
    extern __shared__ unsigned char xs[];        // [TB][LSTR] fp8(e4m3) x tile
    __shared__ float partial[NWAVE][TB];

    const int tid = threadIdx.x;
    const int b0  = blockIdx.x * TB;
    const int p0  = blockIdx.y * PPB;

    // ---- stage x tile (fp32 global, coalesced float4) -> fp8 LDS ----
    #pragma unroll
    for (int i = 0; i < (TB * (F_DIM / 4)) / THREADS; ++i) {   // 16 iters
        const int q   = i * THREADS + tid;
        const int row = q >> 8;
        const int c4  = q & 255;
        const float4 v = *reinterpret_cast<const float4*>(
            x + (size_t)(b0 + row) * F_DIM + (c4 << 2));
        int pk = __builtin_amdgcn_cvt_pk_fp8_f32(v.x, v.y, 0, false);
        pk     = __builtin_amdgcn_cvt_pk_fp8_f32(v.z, v.w, pk, true);
        *reinterpret_cast<uint32_t*>(xs + row * LSTR + (c4 << 2)) = (uint32_t)pk;
    }
    __syncthreads();

    const int lane = tid & 63;           // lane = local batch row
    const int wave = tid >> 6;
    const unsigned char* __restrict__ myrow = xs + lane * LSTR;

    float yacc = 0.0f;

    // 2 patches per iteration: two independent load/compute chains give the
    // scheduler ILP to hide the per-patch scalar-weight (s_load) latency
    for (int jp = 0; jp < PPB / (NWAVE * 2); ++jp) {   // 16 iters
        const int pA = __builtin_amdgcn_readfirstlane(p0 + (jp * NWAVE + wave) * 2);
        const int pB = pA + 1;

        const float loA = patch_eval(myrow, pA, idx, W1, b1, W2, b2, W3, b3);
        const float loB = patch_eval(myrow, pB, idx, W1, b1, W2, b2, W3, b3);

        yacc = fmaf(loA, wl[pA], yacc);
        yacc = fmaf(loB, wl[pB], yacc);
    }

    partial[wave][lane] = yacc;
    __syncthreads();

    // ---- block reduction over the 16 waves + outputs ----
    if (tid < TB) {
        float s = 0.0f;
        #pragma unroll
        for (int w = 0; w < NWAVE; ++w) s += partial[w][tid];
        // two blocks (pgroups) contribute per y element; fp32 add is
        // commutative -> bitwise deterministic regardless of arrival order
        atomicAdd(&out[b0 + tid], s);

        if (blockIdx.y == 0) {
            // channel 2: sum(|w_last|), computed redundantly per row-block
            float sa = 0.0f;
            #pragma unroll
            for (int i = 0; i < P_TOT / TB; ++i) sa += fabsf(wl[tid + TB * i]);
            #pragma unroll
            for (int off = 32; off > 0; off >>= 1) sa += __shfl_down(sa, off);
            sa = __shfl(sa, 0);
            out[B_TOT + b0 + tid] = sa;   // single writer
        }
    }
}

extern "C" void kernel_launch(void* const* d_in, const int* in_sizes, int n_in,
                              void* d_out, int out_size, void* d_ws, size_t ws_size,
                              hipStream_t stream)
{
    const float* x  = (const float*)d_in[0];
    const int*   idx= (const int*)  d_in[1];
    const float* W1 = (const float*)d_in[2];
    const float* b1 = (const float*)d_in[3];
    const float* W2 = (const float*)d_in[4];
    const float* b2 = (const float*)d_in[5];
    const float* W3 = (const float*)d_in[6];
    const float* b3 = (const float*)d_in[7];
    const float* wl = (const float*)d_in[8];
    float* out = (float*)d_out;

    // zero the y channel (atomicAdd accumulates into it)
    (void)hipMemsetAsync(out, 0, B_TOT * sizeof(float), stream);

    const int smem = TB * LSTR;  // 65792 B dynamic LDS (>64KB -> opt in)
    (void)hipFuncSetAttribute(reinterpret_cast<const void*>(dnn_fused),
                              hipFuncAttributeMaxDynamicSharedMemorySize, smem);

    dim3 grid(B_TOT / TB, PGRP);
    dnn_fused<<<grid, THREADS, smem, stream>>>(x, idx, W1, b1, W2, b2, W3, b3, wl, out);
}